// Round 2
// baseline (128.523 us; speedup 1.0000x reference)
//
#include <hip/hip_runtime.h>

#define NN  50000
#define DEG 32
#define DF  128
#define DO  256
#define FEAT4 (NN * DF / 4)   // 1,600,000 float4 groups

typedef __bf16 bf16x8 __attribute__((ext_vector_type(8)));
typedef float  f32x4  __attribute__((ext_vector_type(4)));
typedef float  f32x2  __attribute__((ext_vector_type(2)));
typedef unsigned short u16x8 __attribute__((ext_vector_type(8)));

#if defined(__has_builtin)
#if __has_builtin(__builtin_amdgcn_cvt_pk_f32_fp8) && __has_builtin(__builtin_amdgcn_cvt_pk_fp8_f32)
#define HW_FP8 1
#endif
#endif
#ifndef HW_FP8
#define HW_FP8 0
#endif

__device__ __forceinline__ unsigned short f2bf(float f) {
    unsigned u = __float_as_uint(f);
    u += 0x7FFF + ((u >> 16) & 1);     // round-to-nearest-even
    return (unsigned short)(u >> 16);
}

#if !HW_FP8
__device__ __forceinline__ unsigned enc1_fp8(float f) {
    unsigned u = __float_as_uint(f);
    unsigned s = (u >> 31) << 7;
    float a = fabsf(f);
    if (!(a > 0.f)) return s;
    if (a >= 448.f) return s | 0x7E;
    u = __float_as_uint(a);
    int e = (int)((u >> 23) & 255) - 127;
    if (e < -6) {
        unsigned m = (unsigned)(a * 512.f + 0.5f);
        if (m >= 8) return s | 0x08;
        return s | m;
    }
    unsigned mant = (u >> 20) & 7;
    unsigned rnd  = ((u >> 19) & 1) & (((u & 0x7FFFF) != 0) | ((u >> 20) & 1));
    unsigned enc  = ((unsigned)(e + 7) << 3) | mant;
    return s | (enc + rnd);
}
__device__ __forceinline__ float dec1_fp8(unsigned b) {
    unsigned s = (b >> 7) & 1, e = (b >> 3) & 15, m = b & 7;
    float v = (e == 0) ? (float)m * 0.001953125f
                       : __uint_as_float(((e - 7 + 127) << 23) | (m << 20));
    return s ? -v : v;
}
#endif

__device__ __forceinline__ unsigned enc4_fp8(float4 v) {
#if HW_FP8
    int pk = 0;
    pk = __builtin_amdgcn_cvt_pk_fp8_f32(v.x, v.y, pk, false);
    pk = __builtin_amdgcn_cvt_pk_fp8_f32(v.z, v.w, pk, true);
    return (unsigned)pk;
#else
    return enc1_fp8(v.x) | (enc1_fp8(v.y) << 8) | (enc1_fp8(v.z) << 16) | (enc1_fp8(v.w) << 24);
#endif
}

// ---------------------------------------------------------------------------
// Convert: feat fp32 -> fp8 e4m3 gather table;  W fp32 [K][N] -> Wt bf16 [N][K].
// (featb dropped: the fused kernel converts self rows from fp32 inline, which
//  is bit-identical to the old featb path.)
// ---------------------------------------------------------------------------
__global__ __launch_bounds__(256) void convert_kernel(
    const float* __restrict__ feat, const float* __restrict__ W,
    unsigned* __restrict__ feat8, unsigned short* __restrict__ Wt)
{
    const int gid = blockIdx.x * 256 + threadIdx.x;
    if (gid < FEAT4) {
        const float4 v = ((const float4*)feat)[gid];
        feat8[gid] = enc4_fp8(v);
    } else {
        const int t = gid - FEAT4;
        if (t < DO * DO) {
            const int n = t >> 8, k = t & 255;
            Wt[n * DO + k] = f2bf(W[k * DO + n]);   // write coalesced along k
        }
    }
}

// ---------------------------------------------------------------------------
// Fused aggregation + GEMM.
//  BM=64 nodes, BN=256 (all output cols) per block, 512 threads (8 waves 2x4).
//  Phase 1: mean-of-32 fp8 gather for the block's 64 nodes -> bf16 held in
//           registers (2x u16x8 per thread; 16 lanes/node, 32 nodes/pass).
//  Phase 2: proven 16x16x32 MFMA loop, K in 4 chunks of 64 through LDS:
//           kc=0,1 staged from fp32 feat (inline bf16 convert),
//           kc=2,3 staged from the agg registers (zero global traffic),
//           B chunk staged from Wt (L2-resident).
//  LDS rows padded to 72 bf16 -> worst 2-way quarter-wave conflicts (free).
//  LDS 46 KB -> 3 blocks/CU; gather latency overlaps across resident blocks.
// ---------------------------------------------------------------------------
#define BM  64
#define BN  256
#define LDT 72

__global__ __launch_bounds__(512) void fused_kernel(
    const float*          __restrict__ feat,
    const unsigned*       __restrict__ feat8,
    const int*            __restrict__ edges,
    const unsigned short* __restrict__ Wt,
    float*                __restrict__ out)
{
    __shared__ __align__(16) unsigned short Asw[BM * LDT];
    __shared__ __align__(16) unsigned short Bsw[BN * LDT];

    const int tid = threadIdx.x;
    const int m0  = blockIdx.x * BM;

    // ---- phase 1: aggregate 64 nodes; lane l of each 16-lane group owns
    //      feature cols [8l, 8l+8)
    const int l = tid & 15;
    u16x8 aggr[2];
    #pragma unroll
    for (int pass = 0; pass < 2; ++pass) {
        int node = m0 + pass * 32 + (tid >> 4);
        if (node >= NN) node = NN - 1;
        const int* e = edges + node * DEG;
        float a[8] = {0.f, 0.f, 0.f, 0.f, 0.f, 0.f, 0.f, 0.f};
        #pragma unroll
        for (int d = 0; d < DEG; ++d) {
            const int idx = e[d];
            const uint2 pk = *(const uint2*)(feat8 + (size_t)idx * (DF / 4) + l * 2);
#if HW_FP8
            const f32x2 v0 = __builtin_amdgcn_cvt_pk_f32_fp8((int)pk.x, false);
            const f32x2 v1 = __builtin_amdgcn_cvt_pk_f32_fp8((int)pk.x, true);
            const f32x2 v2 = __builtin_amdgcn_cvt_pk_f32_fp8((int)pk.y, false);
            const f32x2 v3 = __builtin_amdgcn_cvt_pk_f32_fp8((int)pk.y, true);
            a[0] += v0[0]; a[1] += v0[1]; a[2] += v1[0]; a[3] += v1[1];
            a[4] += v2[0]; a[5] += v2[1]; a[6] += v3[0]; a[7] += v3[1];
#else
            #pragma unroll
            for (int j = 0; j < 4; ++j) a[j]     += dec1_fp8((pk.x >> (8 * j)) & 255);
            #pragma unroll
            for (int j = 0; j < 4; ++j) a[4 + j] += dec1_fp8((pk.y >> (8 * j)) & 255);
#endif
        }
        const float s = 1.0f / (float)DEG;
        #pragma unroll
        for (int j = 0; j < 8; ++j) aggr[pass][j] = f2bf(a[j] * s);
    }

    // ---- phase 2: GEMM
    const int wave = tid >> 6, lane = tid & 63;
    const int quad = lane >> 4, lr = lane & 15;
    const int wm   = (wave & 1) * 32;
    const int wn   = (wave >> 1) * 64;

    f32x4 acc[2][4] = {};

    for (int kc = 0; kc < 4; ++kc) {
        __syncthreads();

        if (kc < 2) {
            // A chunk from fp32 self features: 64 rows x 64 cols, 1 seg/thread
            const int r = tid >> 3;
            const int c = (tid & 7) * 8;
            int node = m0 + r;
            if (node >= NN) node = NN - 1;
            const float* src = feat + (size_t)node * DF + kc * 64 + c;
            const float4 v0 = *(const float4*)(src);
            const float4 v1 = *(const float4*)(src + 4);
            u16x8 o;
            o[0] = f2bf(v0.x); o[1] = f2bf(v0.y); o[2] = f2bf(v0.z); o[3] = f2bf(v0.w);
            o[4] = f2bf(v1.x); o[5] = f2bf(v1.y); o[6] = f2bf(v1.z); o[7] = f2bf(v1.w);
            *(u16x8*)(Asw + r * LDT + c) = o;
        } else {
            // A chunk from agg registers: kc=2 -> lanes l<8 (cols 0..63 of agg),
            // kc=3 -> lanes l>=8 (cols 64..127 of agg)
            if ((l >> 3) == (kc - 2)) {
                const int c = (l & 7) * 8;
                #pragma unroll
                for (int pass = 0; pass < 2; ++pass) {
                    const int r = pass * 32 + (tid >> 4);
                    *(u16x8*)(Asw + r * LDT + c) = aggr[pass];
                }
            }
        }

        // B chunk: 256 rows x 64 cols from Wt (L2-resident), 4 segs/thread
        #pragma unroll
        for (int it = 0; it < 4; ++it) {
            const int sidx = it * 512 + tid;
            const int r = sidx >> 3;
            const int c = (sidx & 7) * 8;
            *(u16x8*)(Bsw + r * LDT + c) =
                *(const u16x8*)(Wt + (size_t)r * DO + kc * 64 + c);
        }

        __syncthreads();

        #pragma unroll
        for (int kk = 0; kk < 64; kk += 32) {
            bf16x8 af[2], bfr[4];
            #pragma unroll
            for (int i = 0; i < 2; ++i)
                af[i] = *(const bf16x8*)(Asw + (wm + i * 16 + lr) * LDT + kk + quad * 8);
            #pragma unroll
            for (int i = 0; i < 4; ++i)
                bfr[i] = *(const bf16x8*)(Bsw + (wn + i * 16 + lr) * LDT + kk + quad * 8);
            #pragma unroll
            for (int mi = 0; mi < 2; ++mi)
                #pragma unroll
                for (int ni = 0; ni < 4; ++ni)
                    acc[mi][ni] = __builtin_amdgcn_mfma_f32_16x16x32_bf16(
                        af[mi], bfr[ni], acc[mi][ni], 0, 0, 0);
        }
    }

    // ---- epilogue: relu + store
    #pragma unroll
    for (int mi = 0; mi < 2; ++mi) {
        #pragma unroll
        for (int r = 0; r < 4; ++r) {
            const int row = m0 + wm + mi * 16 + quad * 4 + r;
            if (row < NN) {
                #pragma unroll
                for (int ni = 0; ni < 4; ++ni) {
                    out[(size_t)row * DO + wn + ni * 16 + lr] =
                        fmaxf(acc[mi][ni][r], 0.f);
                }
            }
        }
    }
}

extern "C" void kernel_launch(void* const* d_in, const int* in_sizes, int n_in,
                              void* d_out, int out_size, void* d_ws, size_t ws_size,
                              hipStream_t stream)
{
    const float* feat  = (const float*)d_in[0];
    const int*   edges = (const int*)d_in[1];
    const float* W     = (const float*)d_in[2];
    float*       out   = (float*)d_out;

    unsigned*       feat8 = (unsigned*)d_ws;                          // 6.4 MB
    unsigned short* Wt    = (unsigned short*)(feat8 + (size_t)NN * DF / 4); // 128 KB

    convert_kernel<<<(FEAT4 + DO * DO + 255) / 256, 256, 0, stream>>>(
        feat, W, feat8, Wt);

    fused_kernel<<<(NN + BM - 1) / BM, 512, 0, stream>>>(
        feat, feat8, edges, Wt, out);
}